// Round 1
// baseline (476.601 us; speedup 1.0000x reference)
//
#include <hip/hip_runtime.h>
#include <math.h>

#define NN 100000
#define DD 256
#define BB 4096
#define KK 32
#define INVTEMP (1.0f/0.07f)

// ---------------------------------------------------------------------------
// Aggregate: v[b,d] = masked-mean over k of (nf[nb[b,k],d] + rel[rl[b,k],d]),
// fallback to nf[self[b],d] when count==0. Mask/idx loads are block-uniform.
// grid (B, 2): blockIdx.y selects view. block = 256 (one thread per d).
// ---------------------------------------------------------------------------
__global__ void aggregate_kernel(const float* __restrict__ nf,
                                 const float* __restrict__ rel,
                                 const int* __restrict__ nb1, const int* __restrict__ rl1, const int* __restrict__ mk1,
                                 const int* __restrict__ nb2, const int* __restrict__ rl2, const int* __restrict__ mk2,
                                 const int* __restrict__ self_ids,
                                 float* __restrict__ v1, float* __restrict__ v2) {
  int b = blockIdx.x;
  int d = threadIdx.x;
  const int *nb, *rl, *mk;
  float* out;
  if (blockIdx.y == 0) { nb = nb1; rl = rl1; mk = mk1; out = v1; }
  else                 { nb = nb2; rl = rl2; mk = mk2; out = v2; }
  float acc = 0.f;
  int cnt = 0;
  for (int k = 0; k < KK; ++k) {
    int m = mk[b * KK + k];              // uniform across block
    if (m != 0) {
      int nid = nb[b * KK + k];
      int rid = rl[b * KK + k];
      acc += nf[(long)nid * DD + d] + rel[rid * DD + d];
      cnt++;
    }
  }
  float res;
  if (cnt > 0) res = acc / (float)cnt;
  else         res = nf[(long)self_ids[b] * DD + d];
  out[b * DD + d] = res;
}

// ---------------------------------------------------------------------------
// C[M,N] = act(A[M,K] @ W[K,N] + bias), act = relu if relu!=0.
// Tiles 64x64, TK=16. Block 256 threads (16x16), each computes 4x4.
// M%64==0, N%64==0, K%16==0 assumed.
// ---------------------------------------------------------------------------
__global__ void gemm_bias_act(const float* __restrict__ A, const float* __restrict__ W,
                              const float* __restrict__ bias, float* __restrict__ C,
                              int M, int N, int K, int relu) {
  __shared__ float As[16][68];
  __shared__ float Ws[16][68];
  int tid = threadIdx.x;
  int tx = tid & 15, ty = tid >> 4;
  int row0 = blockIdx.x * 64, col0 = blockIdx.y * 64;
  float acc[4][4] = {};
  for (int k0 = 0; k0 < K; k0 += 16) {
    for (int t = tid; t < 16 * 64; t += 256) {
      int kk = t & 15, mm = t >> 4;       // consecutive t -> consecutive kk (coalesced along K)
      As[kk][mm] = A[(row0 + mm) * K + k0 + kk];
    }
    for (int t = tid; t < 16 * 64; t += 256) {
      int nn = t & 63, kk = t >> 6;       // consecutive t -> consecutive nn (coalesced along N)
      Ws[kk][nn] = W[(k0 + kk) * N + col0 + nn];
    }
    __syncthreads();
#pragma unroll
    for (int kk = 0; kk < 16; ++kk) {
      float a[4], w[4];
#pragma unroll
      for (int i = 0; i < 4; i++) a[i] = As[kk][ty * 4 + i];
#pragma unroll
      for (int j = 0; j < 4; j++) w[j] = Ws[kk][tx * 4 + j];
#pragma unroll
      for (int i = 0; i < 4; i++)
#pragma unroll
        for (int j = 0; j < 4; j++) acc[i][j] += a[i] * w[j];
    }
    __syncthreads();
  }
#pragma unroll
  for (int i = 0; i < 4; i++) {
    int r = row0 + ty * 4 + i;
#pragma unroll
    for (int j = 0; j < 4; j++) {
      int c = col0 + tx * 4 + j;
      float v = acc[i][j] + bias[c];
      if (relu) v = fmaxf(v, 0.f);
      C[r * N + c] = v;
    }
  }
}

// ---------------------------------------------------------------------------
// Row-normalize z (B x 128) in place. grid (B,2), block 128.
// ---------------------------------------------------------------------------
__global__ void normalize_rows(float* __restrict__ z1, float* __restrict__ z2) {
  float* z = blockIdx.y ? z2 : z1;
  int row = blockIdx.x;
  int t = threadIdx.x;
  float v = z[row * 128 + t];
  float s = v * v;
  for (int off = 32; off > 0; off >>= 1) s += __shfl_down(s, off);
  __shared__ float wsum[2];
  if ((t & 63) == 0) wsum[t >> 6] = s;
  __syncthreads();
  float total = wsum[0] + wsum[1];
  z[row * 128 + t] = v / sqrtf(total);
}

// ---------------------------------------------------------------------------
// sim tile (64x64, K=128): s = (z1n . z2n)/TEMP, accumulate exp-sums into
// rowsum/colsum (atomics), write diag (sim_ii) on diagonal tiles.
// ---------------------------------------------------------------------------
__global__ void sim_kernel(const float* __restrict__ z1, const float* __restrict__ z2,
                           float* __restrict__ rowsum, float* __restrict__ colsum,
                           float* __restrict__ diag) {
  __shared__ float As[16][68];
  __shared__ float Bs[16][68];
  __shared__ float red[64][17];
  int tid = threadIdx.x;
  int tx = tid & 15, ty = tid >> 4;
  int row0 = blockIdx.x * 64, col0 = blockIdx.y * 64;
  float acc[4][4] = {};
  for (int k0 = 0; k0 < 128; k0 += 16) {
    for (int t = tid; t < 16 * 64; t += 256) {
      int kk = t & 15, mm = t >> 4;
      As[kk][mm] = z1[(row0 + mm) * 128 + k0 + kk];
      Bs[kk][mm] = z2[(col0 + mm) * 128 + k0 + kk];
    }
    __syncthreads();
#pragma unroll
    for (int kk = 0; kk < 16; ++kk) {
      float a[4], bv[4];
#pragma unroll
      for (int i = 0; i < 4; i++) a[i] = As[kk][ty * 4 + i];
#pragma unroll
      for (int j = 0; j < 4; j++) bv[j] = Bs[kk][tx * 4 + j];
#pragma unroll
      for (int i = 0; i < 4; i++)
#pragma unroll
        for (int j = 0; j < 4; j++) acc[i][j] += a[i] * bv[j];
    }
    __syncthreads();
  }
  float rowpart[4] = {0, 0, 0, 0}, colpart[4] = {0, 0, 0, 0};
#pragma unroll
  for (int i = 0; i < 4; i++)
#pragma unroll
    for (int j = 0; j < 4; j++) {
      float s = acc[i][j] * INVTEMP;
      float e = expf(s);                 // |s| <= 14.3 -> no overflow, no max-sub needed
      rowpart[i] += e;
      colpart[j] += e;
    }
  if (row0 == col0) {
#pragma unroll
    for (int i = 0; i < 4; i++)
#pragma unroll
      for (int j = 0; j < 4; j++)
        if (ty * 4 + i == tx * 4 + j) diag[row0 + ty * 4 + i] = acc[i][j] * INVTEMP;
  }
#pragma unroll
  for (int i = 0; i < 4; i++) red[ty * 4 + i][tx] = rowpart[i];
  __syncthreads();
  if (tid < 64) {
    float s = 0;
    for (int x = 0; x < 16; x++) s += red[tid][x];
    atomicAdd(&rowsum[row0 + tid], s);
  }
  __syncthreads();
#pragma unroll
  for (int j = 0; j < 4; j++) red[tx * 4 + j][ty] = colpart[j];
  __syncthreads();
  if (tid < 64) {
    float s = 0;
    for (int x = 0; x < 16; x++) s += red[tid][x];
    atomicAdd(&colsum[col0 + tid], s);
  }
}

// ---------------------------------------------------------------------------
// loss = mean_i( 0.5*(log(rowsum_i) + log(colsum_i)) - diag_i )
// ---------------------------------------------------------------------------
__global__ void loss_kernel(const float* __restrict__ rowsum, const float* __restrict__ colsum,
                            const float* __restrict__ diag, float* __restrict__ out) {
  int tid = threadIdx.x;
  float acc = 0.f;
  for (int i = tid; i < BB; i += 256)
    acc += 0.5f * (logf(rowsum[i]) + logf(colsum[i])) - diag[i];
  for (int off = 32; off > 0; off >>= 1) acc += __shfl_down(acc, off);
  __shared__ float sbuf[4];
  if ((tid & 63) == 0) sbuf[tid >> 6] = acc;
  __syncthreads();
  if (tid == 0) out[0] = (sbuf[0] + sbuf[1] + sbuf[2] + sbuf[3]) * (1.0f / BB);
}

extern "C" void kernel_launch(void* const* d_in, const int* in_sizes, int n_in,
                              void* d_out, int out_size, void* d_ws, size_t ws_size,
                              hipStream_t stream) {
  const float* nf  = (const float*)d_in[0];
  const float* rel = (const float*)d_in[1];
  const int* nb1 = (const int*)d_in[2];
  const int* rl1 = (const int*)d_in[3];
  const int* mk1 = (const int*)d_in[4];
  const int* nb2 = (const int*)d_in[5];
  const int* rl2 = (const int*)d_in[6];
  const int* mk2 = (const int*)d_in[7];
  const int* self_ids = (const int*)d_in[8];
  const float* W1a = (const float*)d_in[9];
  const float* b1a = (const float*)d_in[10];
  const float* W1b = (const float*)d_in[11];
  const float* b1b = (const float*)d_in[12];
  const float* W2a = (const float*)d_in[13];
  const float* b2a = (const float*)d_in[14];
  const float* W2b = (const float*)d_in[15];
  const float* b2b = (const float*)d_in[16];

  float* v1 = (float*)d_ws;
  float* v2 = v1 + BB * DD;
  float* h1 = v2 + BB * DD;
  float* h2 = h1 + BB * DD;
  float* z1 = h2 + BB * DD;
  float* z2 = z1 + BB * 128;
  float* rowsum = z2 + BB * 128;
  float* colsum = rowsum + BB;
  float* diag   = colsum + BB;

  aggregate_kernel<<<dim3(BB, 2), 256, 0, stream>>>(nf, rel, nb1, rl1, mk1, nb2, rl2, mk2, self_ids, v1, v2);
  gemm_bias_act<<<dim3(BB / 64, DD / 64), 256, 0, stream>>>(v1, W1a, b1a, h1, BB, DD, DD, 1);
  gemm_bias_act<<<dim3(BB / 64, DD / 64), 256, 0, stream>>>(v2, W2a, b2a, h2, BB, DD, DD, 1);
  gemm_bias_act<<<dim3(BB / 64, 128 / 64), 256, 0, stream>>>(h1, W1b, b1b, z1, BB, 128, DD, 0);
  gemm_bias_act<<<dim3(BB / 64, 128 / 64), 256, 0, stream>>>(h2, W2b, b2b, z2, BB, 128, DD, 0);
  normalize_rows<<<dim3(BB, 2), 128, 0, stream>>>(z1, z2);
  hipMemsetAsync(rowsum, 0, 2 * BB * sizeof(float), stream);
  sim_kernel<<<dim3(BB / 64, BB / 64), 256, 0, stream>>>(z1, z2, rowsum, colsum, diag);
  loss_kernel<<<1, 256, 0, stream>>>(rowsum, colsum, diag, (float*)d_out);
}

// Round 2
// 293.722 us; speedup vs baseline: 1.6226x; 1.6226x over previous
//
#include <hip/hip_runtime.h>
#include <hip/hip_bf16.h>
#include <math.h>

#define NN 100000
#define DD 256
#define BB 4096
#define KK 32
#define ZD 128
#define INVTEMP (1.0f/0.07f)

typedef unsigned short u16;
typedef __attribute__((ext_vector_type(8))) short short8;   // 8 x bf16 (4 VGPRs)
typedef __attribute__((ext_vector_type(4))) float floatx4;  // MFMA acc

__device__ inline u16 f2bf(float f) {
  __hip_bfloat16 h = __float2bfloat16(f);
  return *reinterpret_cast<u16*>(&h);
}

// ---------------------------------------------------------------------------
// Weight convert + transpose: Wt[n][k] = bf16(W[k][n]). K fixed = 256 (pow2).
// grid N blocks x 256 threads; output-contiguous writes.
// ---------------------------------------------------------------------------
__global__ void convw_kernel(const float* __restrict__ W, u16* __restrict__ Wt, int N) {
  int idx = blockIdx.x * 256 + threadIdx.x;   // idx over N*256 outputs
  int n = idx >> 8;
  int k = idx & 255;
  Wt[idx] = f2bf(W[k * N + n]);
}

// ---------------------------------------------------------------------------
// Aggregate -> bf16 v. grid (BB, 2). block 256 = 4 k-groups x 64 lanes.
// Group g handles k = 4*kk + g; each iteration the 64 lanes load one full
// 1KB row as float4 (coalesced dwordx4). LDS reduce across groups.
// ---------------------------------------------------------------------------
__global__ void aggregate_kernel(const float* __restrict__ nf,
                                 const float* __restrict__ rel,
                                 const int* __restrict__ nb1, const int* __restrict__ rl1, const int* __restrict__ mk1,
                                 const int* __restrict__ nb2, const int* __restrict__ rl2, const int* __restrict__ mk2,
                                 const int* __restrict__ self_ids,
                                 u16* __restrict__ v1, u16* __restrict__ v2) {
  int b = blockIdx.x;
  const int *nb, *rl, *mk;
  u16* out;
  if (blockIdx.y == 0) { nb = nb1; rl = rl1; mk = mk1; out = v1; }
  else                 { nb = nb2; rl = rl2; mk = mk2; out = v2; }
  int tid = threadIdx.x;
  int g = tid >> 6, c = tid & 63;

  float ax = 0.f, ay = 0.f, az = 0.f, aw = 0.f;
  int cnt = 0;
#pragma unroll
  for (int kk = 0; kk < 8; ++kk) {
    int k = kk * 4 + g;
    if (mk[b * KK + k]) {                       // group-uniform branch
      int nid = nb[b * KK + k];
      int rid = rl[b * KK + k];
      float4 m = *(const float4*)(nf + (size_t)nid * DD + c * 4);
      float4 r = *(const float4*)(rel + (size_t)rid * DD + c * 4);
      ax += m.x + r.x; ay += m.y + r.y; az += m.z + r.z; aw += m.w + r.w;
      cnt++;
    }
  }
  __shared__ float sbuf[4][64][4];
  __shared__ int scnt[4];
  sbuf[g][c][0] = ax; sbuf[g][c][1] = ay; sbuf[g][c][2] = az; sbuf[g][c][3] = aw;
  if (c == 0) scnt[g] = cnt;
  __syncthreads();
  if (g == 0) {
    float sx = sbuf[0][c][0] + sbuf[1][c][0] + sbuf[2][c][0] + sbuf[3][c][0];
    float sy = sbuf[0][c][1] + sbuf[1][c][1] + sbuf[2][c][1] + sbuf[3][c][1];
    float sz = sbuf[0][c][2] + sbuf[1][c][2] + sbuf[2][c][2] + sbuf[3][c][2];
    float sw = sbuf[0][c][3] + sbuf[1][c][3] + sbuf[2][c][3] + sbuf[3][c][3];
    int tot = scnt[0] + scnt[1] + scnt[2] + scnt[3];
    float rx, ry, rz, rw;
    if (tot > 0) {
      float inv = 1.0f / (float)tot;
      rx = sx * inv; ry = sy * inv; rz = sz * inv; rw = sw * inv;
    } else {
      float4 s = *(const float4*)(nf + (size_t)self_ids[b] * DD + c * 4);
      rx = s.x; ry = s.y; rz = s.z; rw = s.w;
    }
    union { u16 us[4]; uint2 u2; } pk;
    pk.us[0] = f2bf(rx); pk.us[1] = f2bf(ry); pk.us[2] = f2bf(rz); pk.us[3] = f2bf(rw);
    *(uint2*)(out + (size_t)b * DD + c * 4) = pk.u2;
  }
}

// ---------------------------------------------------------------------------
// MFMA bt-GEMM: C[M,N] = act(A[M,K] . Bt[N,K]^T + bias)
// 128x128 block tile, 4 waves (2x2), each wave 64x64 = 4x4 MFMA 16x16x32.
// Fragments loaded directly from global (16B per lane). K % 32 == 0.
// ---------------------------------------------------------------------------
template<int RELU, int OUTBF16>
__global__ void mfma_gemm_bt(const u16* __restrict__ A, const u16* __restrict__ Bt,
                             const float* __restrict__ bias, void* __restrict__ C,
                             int M, int N, int K) {
  int tid = threadIdx.x;
  int lane = tid & 63, wid = tid >> 6;
  int m16 = lane & 15, q = lane >> 4;
  int rowbase = blockIdx.x * 128 + (wid >> 1) * 64;
  int colbase = blockIdx.y * 128 + (wid & 1) * 64;
  floatx4 acc[4][4] = {};
  for (int k0 = 0; k0 < K; k0 += 32) {
    short8 a[4], b[4];
#pragma unroll
    for (int i = 0; i < 4; i++)
      a[i] = *(const short8*)(A + (size_t)(rowbase + i * 16 + m16) * K + k0 + q * 8);
#pragma unroll
    for (int j = 0; j < 4; j++)
      b[j] = *(const short8*)(Bt + (size_t)(colbase + j * 16 + m16) * K + k0 + q * 8);
#pragma unroll
    for (int i = 0; i < 4; i++)
#pragma unroll
      for (int j = 0; j < 4; j++)
        acc[i][j] = __builtin_amdgcn_mfma_f32_16x16x32_bf16(a[i], b[j], acc[i][j], 0, 0, 0);
  }
#pragma unroll
  for (int i = 0; i < 4; i++) {
#pragma unroll
    for (int j = 0; j < 4; j++) {
      int col = colbase + j * 16 + m16;
      float bv = bias[col];
#pragma unroll
      for (int r = 0; r < 4; r++) {
        int row = rowbase + i * 16 + q * 4 + r;
        float v = acc[i][j][r] + bv;
        if (RELU) v = fmaxf(v, 0.f);
        if (OUTBF16) ((u16*)C)[(size_t)row * N + col] = f2bf(v);
        else         ((float*)C)[(size_t)row * N + col] = v;
      }
    }
  }
}

// ---------------------------------------------------------------------------
// Normalize rows of z1f/z2f (fp32, [BB][128]) -> bf16 z1/z2; diag_i =
// dot(z1n_i, z2n_i)/TEMP in fp32. One wave (64) per row.
// ---------------------------------------------------------------------------
__global__ void normalize_diag(const float* __restrict__ z1f, const float* __restrict__ z2f,
                               u16* __restrict__ z1, u16* __restrict__ z2,
                               float* __restrict__ diag) {
  int i = blockIdx.x, t = threadIdx.x;
  float2 a = *(const float2*)(z1f + (size_t)i * ZD + t * 2);
  float2 b = *(const float2*)(z2f + (size_t)i * ZD + t * 2);
  float s1 = a.x * a.x + a.y * a.y;
  float s2 = b.x * b.x + b.y * b.y;
#pragma unroll
  for (int off = 1; off < 64; off <<= 1) {
    s1 += __shfl_xor(s1, off);
    s2 += __shfl_xor(s2, off);
  }
  float n1 = rsqrtf(s1), n2 = rsqrtf(s2);
  float ax = a.x * n1, ay = a.y * n1;
  float bx = b.x * n2, by = b.y * n2;
  union { u16 us[2]; unsigned u; } p1, p2;
  p1.us[0] = f2bf(ax); p1.us[1] = f2bf(ay);
  p2.us[0] = f2bf(bx); p2.us[1] = f2bf(by);
  *(unsigned*)(z1 + (size_t)i * ZD + t * 2) = p1.u;
  *(unsigned*)(z2 + (size_t)i * ZD + t * 2) = p2.u;
  float d = ax * bx + ay * by;
#pragma unroll
  for (int off = 1; off < 64; off <<= 1) d += __shfl_xor(d, off);
  if (t == 0) diag[i] = d * INVTEMP;
}

// ---------------------------------------------------------------------------
// sim tile via MFMA: exp((z1n.z2n^T)/TEMP), accumulate row/col exp-sums.
// Same mainloop as gemm (K=128); epilogue: exp + shuffle-reduce + atomics.
// ---------------------------------------------------------------------------
__global__ void sim_kernel(const u16* __restrict__ z1, const u16* __restrict__ z2,
                           float* __restrict__ rowsum, float* __restrict__ colsum) {
  int tid = threadIdx.x;
  int lane = tid & 63, wid = tid >> 6;
  int m16 = lane & 15, q = lane >> 4;
  int rowbase = blockIdx.x * 128 + (wid >> 1) * 64;
  int colbase = blockIdx.y * 128 + (wid & 1) * 64;
  floatx4 acc[4][4] = {};
  for (int k0 = 0; k0 < ZD; k0 += 32) {
    short8 a[4], b[4];
#pragma unroll
    for (int i = 0; i < 4; i++)
      a[i] = *(const short8*)(z1 + (size_t)(rowbase + i * 16 + m16) * ZD + k0 + q * 8);
#pragma unroll
    for (int j = 0; j < 4; j++)
      b[j] = *(const short8*)(z2 + (size_t)(colbase + j * 16 + m16) * ZD + k0 + q * 8);
#pragma unroll
    for (int i = 0; i < 4; i++)
#pragma unroll
      for (int j = 0; j < 4; j++)
        acc[i][j] = __builtin_amdgcn_mfma_f32_16x16x32_bf16(a[i], b[j], acc[i][j], 0, 0, 0);
  }
  float rowacc[4][4] = {};   // [i][r]
  float colacc[4] = {};      // [j]
#pragma unroll
  for (int i = 0; i < 4; i++)
#pragma unroll
    for (int j = 0; j < 4; j++)
#pragma unroll
      for (int r = 0; r < 4; r++) {
        float e = __expf(acc[i][j][r] * INVTEMP);
        rowacc[i][r] += e;
        colacc[j] += e;
      }
  // row reduce across the 16 lanes sharing q (they cover the 16 cols)
#pragma unroll
  for (int off = 1; off <= 8; off <<= 1)
#pragma unroll
    for (int i = 0; i < 4; i++)
#pragma unroll
      for (int r = 0; r < 4; r++) rowacc[i][r] += __shfl_xor(rowacc[i][r], off);
  if (m16 == 0) {
#pragma unroll
    for (int i = 0; i < 4; i++)
#pragma unroll
      for (int r = 0; r < 4; r++)
        atomicAdd(&rowsum[rowbase + i * 16 + q * 4 + r], rowacc[i][r]);
  }
  // col reduce across the 4 quads sharing m16 (they cover the 16 rows)
#pragma unroll
  for (int off = 16; off <= 32; off <<= 1)
#pragma unroll
    for (int j = 0; j < 4; j++) colacc[j] += __shfl_xor(colacc[j], off);
  if (q == 0) {
#pragma unroll
    for (int j = 0; j < 4; j++)
      atomicAdd(&colsum[colbase + j * 16 + m16], colacc[j]);
  }
}

// ---------------------------------------------------------------------------
// loss = mean_i( 0.5*(log(rowsum_i)+log(colsum_i)) - diag_i )
// ---------------------------------------------------------------------------
__global__ void loss_kernel(const float* __restrict__ rowsum, const float* __restrict__ colsum,
                            const float* __restrict__ diag, float* __restrict__ out) {
  int tid = threadIdx.x;
  float acc = 0.f;
  for (int i = tid; i < BB; i += 256)
    acc += 0.5f * (logf(rowsum[i]) + logf(colsum[i])) - diag[i];
#pragma unroll
  for (int off = 1; off < 64; off <<= 1) acc += __shfl_xor(acc, off);
  __shared__ float sbuf[4];
  if ((tid & 63) == 0) sbuf[tid >> 6] = acc;
  __syncthreads();
  if (tid == 0) out[0] = (sbuf[0] + sbuf[1] + sbuf[2] + sbuf[3]) * (1.0f / BB);
}

extern "C" void kernel_launch(void* const* d_in, const int* in_sizes, int n_in,
                              void* d_out, int out_size, void* d_ws, size_t ws_size,
                              hipStream_t stream) {
  const float* nf  = (const float*)d_in[0];
  const float* rel = (const float*)d_in[1];
  const int* nb1 = (const int*)d_in[2];
  const int* rl1 = (const int*)d_in[3];
  const int* mk1 = (const int*)d_in[4];
  const int* nb2 = (const int*)d_in[5];
  const int* rl2 = (const int*)d_in[6];
  const int* mk2 = (const int*)d_in[7];
  const int* self_ids = (const int*)d_in[8];
  const float* W1a = (const float*)d_in[9];
  const float* b1a = (const float*)d_in[10];
  const float* W1b = (const float*)d_in[11];
  const float* b1b = (const float*)d_in[12];
  const float* W2a = (const float*)d_in[13];
  const float* b2a = (const float*)d_in[14];
  const float* W2b = (const float*)d_in[15];
  const float* b2b = (const float*)d_in[16];

  char* ws = (char*)d_ws;
  u16* v1   = (u16*)ws;                 ws += (size_t)BB * DD * 2;   // 2 MB
  u16* v2   = (u16*)ws;                 ws += (size_t)BB * DD * 2;
  u16* h1   = (u16*)ws;                 ws += (size_t)BB * DD * 2;
  u16* h2   = (u16*)ws;                 ws += (size_t)BB * DD * 2;
  float* z1f = (float*)ws;              ws += (size_t)BB * ZD * 4;   // 2 MB
  float* z2f = (float*)ws;              ws += (size_t)BB * ZD * 4;
  u16* z1   = (u16*)ws;                 ws += (size_t)BB * ZD * 2;   // 1 MB
  u16* z2   = (u16*)ws;                 ws += (size_t)BB * ZD * 2;
  u16* W1at = (u16*)ws;                 ws += (size_t)DD * DD * 2;   // 128 KB
  u16* W2at = (u16*)ws;                 ws += (size_t)DD * DD * 2;
  u16* W1bt = (u16*)ws;                 ws += (size_t)ZD * DD * 2;   // 64 KB
  u16* W2bt = (u16*)ws;                 ws += (size_t)ZD * DD * 2;
  float* rowsum = (float*)ws;           ws += (size_t)BB * 4;
  float* colsum = (float*)ws;           ws += (size_t)BB * 4;
  float* diag   = (float*)ws;           ws += (size_t)BB * 4;

  convw_kernel<<<DD, 256, 0, stream>>>(W1a, W1at, DD);   // [256][256] -> [256 n][256 k]
  convw_kernel<<<DD, 256, 0, stream>>>(W2a, W2at, DD);
  convw_kernel<<<ZD, 256, 0, stream>>>(W1b, W1bt, ZD);   // [256][128] -> [128 n][256 k]
  convw_kernel<<<ZD, 256, 0, stream>>>(W2b, W2bt, ZD);

  aggregate_kernel<<<dim3(BB, 2), 256, 0, stream>>>(nf, rel, nb1, rl1, mk1,
                                                    nb2, rl2, mk2, self_ids, v1, v2);

  // h = relu(v @ Wa + ba)  -> bf16
  mfma_gemm_bt<1, 1><<<dim3(BB / 128, DD / 128), 256, 0, stream>>>(v1, W1at, b1a, h1, BB, DD, DD);
  mfma_gemm_bt<1, 1><<<dim3(BB / 128, DD / 128), 256, 0, stream>>>(v2, W2at, b2a, h2, BB, DD, DD);
  // z = h @ Wb + bb        -> fp32
  mfma_gemm_bt<0, 0><<<dim3(BB / 128, ZD / 128), 256, 0, stream>>>(h1, W1bt, b1b, z1f, BB, ZD, DD);
  mfma_gemm_bt<0, 0><<<dim3(BB / 128, ZD / 128), 256, 0, stream>>>(h2, W2bt, b2b, z2f, BB, ZD, DD);

  normalize_diag<<<BB, 64, 0, stream>>>(z1f, z2f, z1, z2, diag);

  hipMemsetAsync(rowsum, 0, 2 * (size_t)BB * sizeof(float), stream);
  sim_kernel<<<dim3(BB / 128, BB / 128), 256, 0, stream>>>(z1, z2, rowsum, colsum);
  loss_kernel<<<1, 256, 0, stream>>>(rowsum, colsum, diag, (float*)d_out);
}

// Round 3
// 255.263 us; speedup vs baseline: 1.8671x; 1.1507x over previous
//
#include <hip/hip_runtime.h>
#include <hip/hip_bf16.h>
#include <math.h>

#define NN 100000
#define DD 256
#define BB 4096
#define KK 32
#define ZD 128
#define INVTEMP (1.0f/0.07f)
#define HS 264   // LDS row stride for h tile (bf16): 256 + 8 pad -> 2-way conflicts only

typedef unsigned short u16;
typedef __attribute__((ext_vector_type(8))) short short8;   // 8 x bf16 (4 VGPRs)
typedef __attribute__((ext_vector_type(4))) float floatx4;  // MFMA acc

__device__ inline u16 f2bf(float f) {
  __hip_bfloat16 h = __float2bfloat16(f);
  return *reinterpret_cast<u16*>(&h);
}

// ---------------------------------------------------------------------------
// All 4 weight converts in one launch. Wt[n][k] = bf16(W[k][n]).
// W1a/W2a: [256][256] -> 65536 elems each. W1b/W2b: [256][128] -> 32768 each.
// Total 196608 elems = 768 blocks x 256.
// ---------------------------------------------------------------------------
__global__ void convw_all(const float* __restrict__ W1a, const float* __restrict__ W2a,
                          const float* __restrict__ W1b, const float* __restrict__ W2b,
                          u16* __restrict__ W1at, u16* __restrict__ W2at,
                          u16* __restrict__ W1bt, u16* __restrict__ W2bt) {
  int idx = blockIdx.x * 256 + threadIdx.x;
  const float* W; u16* Wt; int N, off;
  if (idx < 65536)       { W = W1a; Wt = W1at; N = 256; off = idx; }
  else if (idx < 131072) { W = W2a; Wt = W2at; N = 256; off = idx - 65536; }
  else if (idx < 163840) { W = W1b; Wt = W1bt; N = 128; off = idx - 131072; }
  else                   { W = W2b; Wt = W2bt; N = 128; off = idx - 163840; }
  int n = off >> 8, k = off & 255;
  Wt[off] = f2bf(W[k * N + n]);
}

// ---------------------------------------------------------------------------
// Aggregate -> bf16 v. grid (BB, 2). block 256 = 4 k-groups x 64 lanes.
// ---------------------------------------------------------------------------
__global__ void aggregate_kernel(const float* __restrict__ nf,
                                 const float* __restrict__ rel,
                                 const int* __restrict__ nb1, const int* __restrict__ rl1, const int* __restrict__ mk1,
                                 const int* __restrict__ nb2, const int* __restrict__ rl2, const int* __restrict__ mk2,
                                 const int* __restrict__ self_ids,
                                 u16* __restrict__ v1, u16* __restrict__ v2) {
  int b = blockIdx.x;
  const int *nb, *rl, *mk;
  u16* out;
  if (blockIdx.y == 0) { nb = nb1; rl = rl1; mk = mk1; out = v1; }
  else                 { nb = nb2; rl = rl2; mk = mk2; out = v2; }
  int tid = threadIdx.x;
  int g = tid >> 6, c = tid & 63;

  float ax = 0.f, ay = 0.f, az = 0.f, aw = 0.f;
  int cnt = 0;
#pragma unroll
  for (int kk = 0; kk < 8; ++kk) {
    int k = kk * 4 + g;
    if (mk[b * KK + k]) {                       // wave-uniform branch
      int nid = nb[b * KK + k];
      int rid = rl[b * KK + k];
      float4 m = *(const float4*)(nf + (size_t)nid * DD + c * 4);
      float4 r = *(const float4*)(rel + (size_t)rid * DD + c * 4);
      ax += m.x + r.x; ay += m.y + r.y; az += m.z + r.z; aw += m.w + r.w;
      cnt++;
    }
  }
  __shared__ float sbuf[4][64][4];
  __shared__ int scnt[4];
  sbuf[g][c][0] = ax; sbuf[g][c][1] = ay; sbuf[g][c][2] = az; sbuf[g][c][3] = aw;
  if (c == 0) scnt[g] = cnt;
  __syncthreads();
  if (g == 0) {
    float sx = sbuf[0][c][0] + sbuf[1][c][0] + sbuf[2][c][0] + sbuf[3][c][0];
    float sy = sbuf[0][c][1] + sbuf[1][c][1] + sbuf[2][c][1] + sbuf[3][c][1];
    float sz = sbuf[0][c][2] + sbuf[1][c][2] + sbuf[2][c][2] + sbuf[3][c][2];
    float sw = sbuf[0][c][3] + sbuf[1][c][3] + sbuf[2][c][3] + sbuf[3][c][3];
    int tot = scnt[0] + scnt[1] + scnt[2] + scnt[3];
    float rx, ry, rz, rw;
    if (tot > 0) {
      float inv = 1.0f / (float)tot;
      rx = sx * inv; ry = sy * inv; rz = sz * inv; rw = sw * inv;
    } else {
      float4 s = *(const float4*)(nf + (size_t)self_ids[b] * DD + c * 4);
      rx = s.x; ry = s.y; rz = s.z; rw = s.w;
    }
    union { u16 us[4]; uint2 u2; } pk;
    pk.us[0] = f2bf(rx); pk.us[1] = f2bf(ry); pk.us[2] = f2bf(rz); pk.us[3] = f2bf(rw);
    *(uint2*)(out + (size_t)b * DD + c * 4) = pk.u2;
  }
}

// ---------------------------------------------------------------------------
// Fused projection: z = relu(v @ Wa + ba) @ Wb + bb, per 128-row block.
// Phase 1: h tile (128x256 bf16) -> LDS. Phase 2: z tile (128x128 fp32) ->
// global. 4 waves in 2x2; each wave 64x64 via 4x4 MFMA 16x16x32.
// grid (BB/128, 2): blockIdx.y = view.
// ---------------------------------------------------------------------------
__global__ void __launch_bounds__(256, 1)
proj_fused(const u16* __restrict__ v1, const u16* __restrict__ v2,
           const u16* __restrict__ W1at, const u16* __restrict__ W2at,
           const float* __restrict__ b1a, const float* __restrict__ b2a,
           const u16* __restrict__ W1bt, const u16* __restrict__ W2bt,
           const float* __restrict__ b1b, const float* __restrict__ b2b,
           float* __restrict__ z1f, float* __restrict__ z2f) {
  const u16 *v, *Wat, *Wbt;
  const float *ba, *bb;
  float* zf;
  if (blockIdx.y == 0) { v = v1; Wat = W1at; ba = b1a; Wbt = W1bt; bb = b1b; zf = z1f; }
  else                 { v = v2; Wat = W2at; ba = b2a; Wbt = W2bt; bb = b2b; zf = z2f; }
  __shared__ u16 hs[128 * HS];
  int tid = threadIdx.x;
  int lane = tid & 63, wid = tid >> 6;
  int m16 = lane & 15, q = lane >> 4;
  int rh = wid >> 1, ch = wid & 1;
  int M0 = blockIdx.x * 128;
  int rowl = rh * 64;                 // block-local row base for this wave

  // ---- phase 1: h = relu(v @ Wa + ba), two 128-col tiles ----
  for (int nt = 0; nt < 2; ++nt) {
    int colb = nt * 128 + ch * 64;
    floatx4 acc[4][4] = {};
    for (int k0 = 0; k0 < DD; k0 += 32) {
      short8 a[4], b[4];
#pragma unroll
      for (int i = 0; i < 4; i++)
        a[i] = *(const short8*)(v + (size_t)(M0 + rowl + i * 16 + m16) * DD + k0 + q * 8);
#pragma unroll
      for (int j = 0; j < 4; j++)
        b[j] = *(const short8*)(Wat + (size_t)(colb + j * 16 + m16) * DD + k0 + q * 8);
#pragma unroll
      for (int i = 0; i < 4; i++)
#pragma unroll
        for (int j = 0; j < 4; j++)
          acc[i][j] = __builtin_amdgcn_mfma_f32_16x16x32_bf16(a[i], b[j], acc[i][j], 0, 0, 0);
    }
#pragma unroll
    for (int i = 0; i < 4; i++)
#pragma unroll
      for (int j = 0; j < 4; j++) {
        int col = colb + j * 16 + m16;
        float bv = ba[col];
#pragma unroll
        for (int r = 0; r < 4; r++) {
          int row = rowl + i * 16 + q * 4 + r;
          hs[row * HS + col] = f2bf(fmaxf(acc[i][j][r] + bv, 0.f));
        }
      }
  }
  __syncthreads();

  // ---- phase 2: z = h @ Wb + bb (N=128, single col tile) ----
  {
    int colb = ch * 64;
    floatx4 acc[4][4] = {};
    for (int k0 = 0; k0 < DD; k0 += 32) {
      short8 a[4], b[4];
#pragma unroll
      for (int i = 0; i < 4; i++)
        a[i] = *(const short8*)(hs + (rowl + i * 16 + m16) * HS + k0 + q * 8);
#pragma unroll
      for (int j = 0; j < 4; j++)
        b[j] = *(const short8*)(Wbt + (size_t)(colb + j * 16 + m16) * DD + k0 + q * 8);
#pragma unroll
      for (int i = 0; i < 4; i++)
#pragma unroll
        for (int j = 0; j < 4; j++)
          acc[i][j] = __builtin_amdgcn_mfma_f32_16x16x32_bf16(a[i], b[j], acc[i][j], 0, 0, 0);
    }
#pragma unroll
    for (int i = 0; i < 4; i++)
#pragma unroll
      for (int j = 0; j < 4; j++) {
        int col = colb + j * 16 + m16;
        float bv = bb[col];
#pragma unroll
        for (int r = 0; r < 4; r++) {
          int row = M0 + rowl + i * 16 + q * 4 + r;
          zf[(size_t)row * ZD + col] = acc[i][j][r] + bv;
        }
      }
  }
}

// ---------------------------------------------------------------------------
// Normalize rows -> bf16 z, diag in fp32; also zero rowsum/colsum for sim.
// One wave per row, grid BB.
// ---------------------------------------------------------------------------
__global__ void normalize_diag(const float* __restrict__ z1f, const float* __restrict__ z2f,
                               u16* __restrict__ z1, u16* __restrict__ z2,
                               float* __restrict__ diag,
                               float* __restrict__ rowsum, float* __restrict__ colsum) {
  int i = blockIdx.x, t = threadIdx.x;
  if (t == 0) { rowsum[i] = 0.f; colsum[i] = 0.f; }
  float2 a = *(const float2*)(z1f + (size_t)i * ZD + t * 2);
  float2 b = *(const float2*)(z2f + (size_t)i * ZD + t * 2);
  float s1 = a.x * a.x + a.y * a.y;
  float s2 = b.x * b.x + b.y * b.y;
#pragma unroll
  for (int off = 1; off < 64; off <<= 1) {
    s1 += __shfl_xor(s1, off);
    s2 += __shfl_xor(s2, off);
  }
  float n1 = rsqrtf(s1), n2 = rsqrtf(s2);
  float ax = a.x * n1, ay = a.y * n1;
  float bx = b.x * n2, by = b.y * n2;
  union { u16 us[2]; unsigned u; } p1, p2;
  p1.us[0] = f2bf(ax); p1.us[1] = f2bf(ay);
  p2.us[0] = f2bf(bx); p2.us[1] = f2bf(by);
  *(unsigned*)(z1 + (size_t)i * ZD + t * 2) = p1.u;
  *(unsigned*)(z2 + (size_t)i * ZD + t * 2) = p2.u;
  float d = ax * bx + ay * by;
#pragma unroll
  for (int off = 1; off < 64; off <<= 1) d += __shfl_xor(d, off);
  if (t == 0) diag[i] = d * INVTEMP;
}

// ---------------------------------------------------------------------------
// sim tile via MFMA: exp((z1n.z2n^T)/TEMP), row/col exp-sums via shuffle +
// one atomic per row/col per wave.
// ---------------------------------------------------------------------------
__global__ void __launch_bounds__(256, 2)
sim_kernel(const u16* __restrict__ z1, const u16* __restrict__ z2,
           float* __restrict__ rowsum, float* __restrict__ colsum) {
  int tid = threadIdx.x;
  int lane = tid & 63, wid = tid >> 6;
  int m16 = lane & 15, q = lane >> 4;
  int rowbase = blockIdx.x * 128 + (wid >> 1) * 64;
  int colbase = blockIdx.y * 128 + (wid & 1) * 64;
  floatx4 acc[4][4] = {};
  for (int k0 = 0; k0 < ZD; k0 += 32) {
    short8 a[4], b[4];
#pragma unroll
    for (int i = 0; i < 4; i++)
      a[i] = *(const short8*)(z1 + (size_t)(rowbase + i * 16 + m16) * ZD + k0 + q * 8);
#pragma unroll
    for (int j = 0; j < 4; j++)
      b[j] = *(const short8*)(z2 + (size_t)(colbase + j * 16 + m16) * ZD + k0 + q * 8);
#pragma unroll
    for (int i = 0; i < 4; i++)
#pragma unroll
      for (int j = 0; j < 4; j++)
        acc[i][j] = __builtin_amdgcn_mfma_f32_16x16x32_bf16(a[i], b[j], acc[i][j], 0, 0, 0);
  }
  float rowacc[4][4] = {};   // [i][r]
  float colacc[4] = {};      // [j]
#pragma unroll
  for (int i = 0; i < 4; i++)
#pragma unroll
    for (int j = 0; j < 4; j++)
#pragma unroll
      for (int r = 0; r < 4; r++) {
        float e = __expf(acc[i][j][r] * INVTEMP);
        rowacc[i][r] += e;
        colacc[j] += e;
      }
#pragma unroll
  for (int off = 1; off <= 8; off <<= 1)
#pragma unroll
    for (int i = 0; i < 4; i++)
#pragma unroll
      for (int r = 0; r < 4; r++) rowacc[i][r] += __shfl_xor(rowacc[i][r], off);
  if (m16 == 0) {
#pragma unroll
    for (int i = 0; i < 4; i++)
#pragma unroll
      for (int r = 0; r < 4; r++)
        atomicAdd(&rowsum[rowbase + i * 16 + q * 4 + r], rowacc[i][r]);
  }
#pragma unroll
  for (int off = 16; off <= 32; off <<= 1)
#pragma unroll
    for (int j = 0; j < 4; j++) colacc[j] += __shfl_xor(colacc[j], off);
  if (q == 0) {
#pragma unroll
    for (int j = 0; j < 4; j++)
      atomicAdd(&colsum[colbase + j * 16 + m16], colacc[j]);
  }
}

// ---------------------------------------------------------------------------
// loss = mean_i( 0.5*(log(rowsum_i)+log(colsum_i)) - diag_i )
// ---------------------------------------------------------------------------
__global__ void loss_kernel(const float* __restrict__ rowsum, const float* __restrict__ colsum,
                            const float* __restrict__ diag, float* __restrict__ out) {
  int tid = threadIdx.x;
  float acc = 0.f;
  for (int i = tid; i < BB; i += 256)
    acc += 0.5f * (logf(rowsum[i]) + logf(colsum[i])) - diag[i];
#pragma unroll
  for (int off = 1; off < 64; off <<= 1) acc += __shfl_xor(acc, off);
  __shared__ float sbuf[4];
  if ((tid & 63) == 0) sbuf[tid >> 6] = acc;
  __syncthreads();
  if (tid == 0) out[0] = (sbuf[0] + sbuf[1] + sbuf[2] + sbuf[3]) * (1.0f / BB);
}

extern "C" void kernel_launch(void* const* d_in, const int* in_sizes, int n_in,
                              void* d_out, int out_size, void* d_ws, size_t ws_size,
                              hipStream_t stream) {
  const float* nf  = (const float*)d_in[0];
  const float* rel = (const float*)d_in[1];
  const int* nb1 = (const int*)d_in[2];
  const int* rl1 = (const int*)d_in[3];
  const int* mk1 = (const int*)d_in[4];
  const int* nb2 = (const int*)d_in[5];
  const int* rl2 = (const int*)d_in[6];
  const int* mk2 = (const int*)d_in[7];
  const int* self_ids = (const int*)d_in[8];
  const float* W1a = (const float*)d_in[9];
  const float* b1a = (const float*)d_in[10];
  const float* W1b = (const float*)d_in[11];
  const float* b1b = (const float*)d_in[12];
  const float* W2a = (const float*)d_in[13];
  const float* b2a = (const float*)d_in[14];
  const float* W2b = (const float*)d_in[15];
  const float* b2b = (const float*)d_in[16];

  char* ws = (char*)d_ws;
  u16* v1   = (u16*)ws;                 ws += (size_t)BB * DD * 2;
  u16* v2   = (u16*)ws;                 ws += (size_t)BB * DD * 2;
  float* z1f = (float*)ws;              ws += (size_t)BB * ZD * 4;
  float* z2f = (float*)ws;              ws += (size_t)BB * ZD * 4;
  u16* z1   = (u16*)ws;                 ws += (size_t)BB * ZD * 2;
  u16* z2   = (u16*)ws;                 ws += (size_t)BB * ZD * 2;
  u16* W1at = (u16*)ws;                 ws += (size_t)DD * DD * 2;
  u16* W2at = (u16*)ws;                 ws += (size_t)DD * DD * 2;
  u16* W1bt = (u16*)ws;                 ws += (size_t)ZD * DD * 2;
  u16* W2bt = (u16*)ws;                 ws += (size_t)ZD * DD * 2;
  float* rowsum = (float*)ws;           ws += (size_t)BB * 4;
  float* colsum = (float*)ws;           ws += (size_t)BB * 4;
  float* diag   = (float*)ws;           ws += (size_t)BB * 4;

  convw_all<<<768, 256, 0, stream>>>(W1a, W2a, W1b, W2b, W1at, W2at, W1bt, W2bt);
  aggregate_kernel<<<dim3(BB, 2), 256, 0, stream>>>(nf, rel, nb1, rl1, mk1,
                                                    nb2, rl2, mk2, self_ids, v1, v2);
  proj_fused<<<dim3(BB / 128, 2), 256, 0, stream>>>(v1, v2, W1at, W2at, b1a, b2a,
                                                    W1bt, W2bt, b1b, b2b, z1f, z2f);
  normalize_diag<<<BB, 64, 0, stream>>>(z1f, z2f, z1, z2, diag, rowsum, colsum);
  sim_kernel<<<dim3(BB / 128, BB / 128), 256, 0, stream>>>(z1, z2, rowsum, colsum);
  loss_kernel<<<1, 256, 0, stream>>>(rowsum, colsum, diag, (float*)d_out);
}